// Round 12
// baseline (170.841 us; speedup 1.0000x reference)
//
#include <hip/hip_runtime.h>
#include <math.h>

#define N_ATOMS    30000
#define N_PAIRS    300000
#define CAP        48              // bucket capacity per atom; multiple of 16
#define NF         64
#define ND         20
#define K_ENV      1280            // 20nu * 64f (packed, no padding)
#define K_TOT      1344            // K_ENV + 64 self features
#define NKSTEP     42              // K_TOT / 32
#define HARD_CUT   6.5f
#define BA         16              // atoms per block in main kernel
#define ESTRIDE    1352            // env row stride in u16 (1344+8 pad -> bank spread)
#define D_LO       0.85f
#define D_SCALE    (5.65f / 65535.0f)
#define D_SCALE_I  (65535.0f / 5.65f)
#define NM1        ((unsigned)(N_ATOMS - 1))

typedef short    s16x8  __attribute__((ext_vector_type(8)));
typedef __bf16   bf16x8 __attribute__((ext_vector_type(8)));
typedef unsigned u32x4  __attribute__((ext_vector_type(4)));
typedef float    f32x4  __attribute__((ext_vector_type(4)));
typedef float    f32x16 __attribute__((ext_vector_type(16)));

__device__ __forceinline__ unsigned short f2bf(float x) {
    union { float f; unsigned u; } v; v.f = x;
    unsigned r = v.u + 0x7fffu + ((v.u >> 16) & 1u);   // RNE
    return (unsigned short)(r >> 16);
}
// pack two floats -> packed bf16 pair (a in low 16), RNE
__device__ __forceinline__ unsigned pkbf(float a, float b) {
    return (unsigned)f2bf(a) | ((unsigned)f2bf(b) << 16);
}
// sensitivity for one packed pair-slot, lane's nu
__device__ __forceinline__ float senseval(unsigned pu, int kidx, int cnt,
                                          float isig, float musig, bool nuok) {
    float d  = D_LO + (float)(pu & 0xffffu) * D_SCALE;
    float z  = __builtin_amdgcn_rcpf(d) * isig - musig;
    float co = __cosf(0.2416609733530613f * d);        // 0.5*pi/6.5
    float e  = __expf(-0.5f * z * z) * (co * co);
    return (nuok && kidx < cnt) ? e : 0.0f;
}

// ---------------------------------------------------------------------------
// K0: prep = pack weights into bf16 B-frag layout with phase-1 k'-permutation
// (blocks 0..41), zero cnts (42..159), msr (160).
// k' < 1280: t=k'/640, g=(k'%640)>>7, c=(k'&127)>>2, r=k'&3 -> nu=4g+r, f=2c+t
//            (even/odd feature split -> phase-1 dwordx2 gathers; verified R9)
// k' >=1280: self row, f = k'-1280.
__global__ void k_prep(const float* __restrict__ iw, const float* __restrict__ wself,
                       const float* __restrict__ mu, const float* __restrict__ sigma,
                       unsigned short* __restrict__ WtB, int* __restrict__ cnts,
                       float2* __restrict__ msr) {
    if (blockIdx.x < 42) {
        int idx = blockIdx.x * 256 + threadIdx.x;       // (ks*4+q)*64 + lane
        if (idx >= NKSTEP * 4 * 64) return;
        int l  = idx & 63;
        int q  = (idx >> 6) & 3;
        int ks = idx >> 8;
        int n  = q * 16 + (l & 15);
        int kb = ks * 32 + (l >> 4) * 8;
        u32x4 u;
        #pragma unroll
        for (int jj = 0; jj < 4; jj++) {
            unsigned short lo, hi;
            #pragma unroll
            for (int e = 0; e < 2; e++) {
                int k = kb + 2 * jj + e;
                float val;
                if (k < K_ENV) {
                    int t  = k / 640;
                    int rm = k - t * 640;
                    int g  = rm >> 7;
                    int c  = (rm & 127) >> 2;
                    int r  = k & 3;
                    int nu = 4 * g + r;
                    int f  = 2 * c + t;                  // even/odd tile split
                    val = iw[(nu * NF + n) * NF + f];
                } else {
                    val = wself[n * NF + (k - K_ENV)];
                }
                if (e == 0) lo = f2bf(val); else hi = f2bf(val);
            }
            u[jj] = (unsigned)lo | ((unsigned)hi << 16);
        }
        *(u32x4*)&WtB[idx * 8] = u;
    } else if (blockIdx.x < 160) {
        int i = (blockIdx.x - 42) * 256 + threadIdx.x;
        if (i < N_ATOMS) cnts[i] = 0;
    } else {
        int i = threadIdx.x;
        if (i < ND) { float2 m; m.x = mu[i]; m.y = 1.0f / sigma[i]; msr[i] = m; }
    }
}

// ---------------------------------------------------------------------------
// K1: scatter pairs into per-atom buckets; pack (second<<16 | dist_u16).
// 2 pairs/thread, vectorized input loads.
__global__ void k_scatter(const int* __restrict__ first, const int* __restrict__ second,
                          const float* __restrict__ dist, int* __restrict__ cnts,
                          unsigned* __restrict__ pk) {
    int p = (blockIdx.x * 256 + threadIdx.x) * 2;
    if (p >= N_PAIRS) return;
    int2   f2 = *(const int2*)&first[p];
    int2   s2 = *(const int2*)&second[p];
    float2 d2 = *(const float2*)&dist[p];
    {
        int pos = atomicAdd(&cnts[f2.x], 1);
        if (pos < CAP) {
            unsigned du = min((unsigned)((d2.x - D_LO) * D_SCALE_I + 0.5f), 65535u);
            pk[(size_t)f2.x * CAP + pos] = ((unsigned)s2.x << 16) | du;
        }
    }
    {
        int pos = atomicAdd(&cnts[f2.y], 1);
        if (pos < CAP) {
            unsigned du = min((unsigned)((d2.y - D_LO) * D_SCALE_I + 0.5f), 65535u);
            pk[(size_t)f2.y * CAP + pos] = ((unsigned)s2.y << 16) | du;
        }
    }
}

// ---------------------------------------------------------------------------
// K2: fused sense + MFMA envsum + MFMA interaction matmul. 512 thr = 8 waves.
// All staging in ext-vectors / named scalars (no allocas -> no scratch; R10/R11).
// Phase 1: wave w handles atoms {2w,2w+1}; BOTH atoms' counts (int2), first
//   K-step p-vectors and self rows are loaded up front so atom 1's memory
//   chain overlaps atom 0's compute (front-end MLP). Per 16-pair K-step:
//   A = sense^T (8 exps inline), B = x rows via dwordx2 (feats {2cl,2cl+1}
//   -> even/odd tiles), 2x mfma_f32_32x32x16_bf16; C -> LDS in C-layout.
// Phase 2: waves 0..3: out[16 atoms][64] = env[16][1344] x WtB (16x16x32).
__global__ void __launch_bounds__(512, 6)
k_main(const float* __restrict__ x, const int* __restrict__ cnts,
       const unsigned* __restrict__ pk, const float2* __restrict__ msr,
       const unsigned short* __restrict__ WtB, const float* __restrict__ bself,
       float* __restrict__ out) {
    __shared__ unsigned short env[BA * ESTRIDE];          // 43264 B -> 3 blocks/CU
    const int t  = threadIdx.x;
    const int w  = t >> 6;       // wave 0..7
    const int l  = t & 63;       // lane
    const int h  = l >> 5;       // half-wave (k-group)
    const int cl = l & 31;       // A: nu row   |  B/C: column
    const int a0 = blockIdx.x * BA;

    // lane-resident sense constants (nu = cl)
    float2 ms   = msr[min(cl, ND - 1)];
    const float isig  = ms.y;
    const float musig = ms.x * ms.y;
    const bool  nuok  = (cl < ND);
    const float* xb = x + 2 * cl;

    // ---- Phase 1 front end: both atoms' loads issued together (MLP) ----
    const int aw = a0 + 2 * w;
    int2 cc2 = *(const int2*)&cnts[aw];                   // aw even -> aligned
    const float self0 = x[(size_t)aw * NF + l];
    const float self1 = x[(size_t)(aw + 1) * NF + l];
    const unsigned* gb0 = &pk[(size_t)aw * CAP];
    const unsigned* gb1 = gb0 + CAP;
    uint4 pf00 = *(const uint4*)(gb0 + h * 8);            // atom0 step0
    uint4 pf01 = *(const uint4*)(gb0 + h * 8 + 4);
    uint4 pf10 = *(const uint4*)(gb1 + h * 8);            // atom1 step0 (prefetch)
    uint4 pf11 = *(const uint4*)(gb1 + h * 8 + 4);

    #pragma unroll 1
    for (int ci = 0; ci < 2; ci++) {
        const int i = 2 * w + ci;
        const int cnt = min(ci ? cc2.y : cc2.x, CAP);
        const int nst = max((cnt + 15) >> 4, 1);
        const unsigned* gb = ci ? gb1 : gb0;
        uint4 p0 = ci ? pf10 : pf00;
        uint4 p1 = ci ? pf11 : pf01;
        f32x16 acc0 = {0.f}, acc1 = {0.f};
        #pragma unroll 1
        for (int ks = 0; ks < nst; ks++) {
            const int k0 = ks * 16 + h * 8;
            if (ks) {
                p0 = *(const uint4*)(gb + k0);            // 16B-aligned, h-uniform
                p1 = *(const uint4*)(gb + k0 + 4);
            }
            // 8 dwordx2 gathers, named scalars (no array -> no alloca)
            float2 b0 = *(const float2*)&xb[min(p0.x >> 16, NM1) * NF];
            float2 b1 = *(const float2*)&xb[min(p0.y >> 16, NM1) * NF];
            float2 b2 = *(const float2*)&xb[min(p0.z >> 16, NM1) * NF];
            float2 b3 = *(const float2*)&xb[min(p0.w >> 16, NM1) * NF];
            float2 b4 = *(const float2*)&xb[min(p1.x >> 16, NM1) * NF];
            float2 b5 = *(const float2*)&xb[min(p1.y >> 16, NM1) * NF];
            float2 b6 = *(const float2*)&xb[min(p1.z >> 16, NM1) * NF];
            float2 b7 = *(const float2*)&xb[min(p1.w >> 16, NM1) * NF];
            u32x4 A, B0, B1;
            A[0] = pkbf(senseval(p0.x, k0 + 0, cnt, isig, musig, nuok),
                        senseval(p0.y, k0 + 1, cnt, isig, musig, nuok));
            A[1] = pkbf(senseval(p0.z, k0 + 2, cnt, isig, musig, nuok),
                        senseval(p0.w, k0 + 3, cnt, isig, musig, nuok));
            A[2] = pkbf(senseval(p1.x, k0 + 4, cnt, isig, musig, nuok),
                        senseval(p1.y, k0 + 5, cnt, isig, musig, nuok));
            A[3] = pkbf(senseval(p1.z, k0 + 6, cnt, isig, musig, nuok),
                        senseval(p1.w, k0 + 7, cnt, isig, musig, nuok));
            B0[0] = pkbf(b0.x, b1.x); B0[1] = pkbf(b2.x, b3.x);
            B0[2] = pkbf(b4.x, b5.x); B0[3] = pkbf(b6.x, b7.x);   // even feats
            B1[0] = pkbf(b0.y, b1.y); B1[1] = pkbf(b2.y, b3.y);
            B1[2] = pkbf(b4.y, b5.y); B1[3] = pkbf(b6.y, b7.y);   // odd feats
            acc0 = __builtin_amdgcn_mfma_f32_32x32x16_bf16(
                       __builtin_bit_cast(bf16x8, A),
                       __builtin_bit_cast(bf16x8, B0), acc0, 0, 0, 0);
            acc1 = __builtin_amdgcn_mfma_f32_32x32x16_bf16(
                       __builtin_bit_cast(bf16x8, A),
                       __builtin_bit_cast(bf16x8, B1), acc1, 0, 0, 0);
        }
        // C -> env LDS. C row = (reg&3)+8*(reg>>2)+4*h; g=2q+h holds rows
        // 4g..4g+3 (g<5 <=> row<20). k' = t*640 + g*128 + cl*4 + r.
        unsigned short* er = &env[i * ESTRIDE];
        #pragma unroll
        for (int q = 0; q < 3; q++) {
            int g = 2 * q + h;
            if (g < 5) {
                uint2 v0, v1;
                v0.x = pkbf(acc0[4 * q + 0], acc0[4 * q + 1]);
                v0.y = pkbf(acc0[4 * q + 2], acc0[4 * q + 3]);
                v1.x = pkbf(acc1[4 * q + 0], acc1[4 * q + 1]);
                v1.y = pkbf(acc1[4 * q + 2], acc1[4 * q + 3]);
                *(uint2*)&er[g * 128 + cl * 4]       = v0;
                *(uint2*)&er[640 + g * 128 + cl * 4] = v1;
            }
        }
        er[K_ENV + l] = f2bf(ci ? self1 : self0);         // self features
    }
    __syncthreads();

    // ---- Phase 2: MFMA GEMM (waves 0..3) ----
    if (w < 4) {
        const int m16  = l & 15;     // atom row / out col
        const int quad = l >> 4;
        f32x4 acc = {0.f, 0.f, 0.f, 0.f};
        for (int ks = 0; ks < NKSTEP; ks++) {
            s16x8 afrag = *(const s16x8*)&env[m16 * ESTRIDE + ks * 32 + quad * 8];
            s16x8 bfrag = *(const s16x8*)&WtB[((ks * 4 + w) * 64 + l) * 8];
            acc = __builtin_amdgcn_mfma_f32_16x16x32_bf16(
                      __builtin_bit_cast(bf16x8, afrag),
                      __builtin_bit_cast(bf16x8, bfrag), acc, 0, 0, 0);
        }
        const float bs = bself[w * 16 + m16];
        #pragma unroll
        for (int r = 0; r < 4; r++) {
            int row = quad * 4 + r;                       // atom within block
            out[(size_t)(a0 + row) * NF + w * 16 + m16] = acc[r] + bs;
        }
    }
}

// ---------------------------------------------------------------------------
extern "C" void kernel_launch(void* const* d_in, const int* in_sizes, int n_in,
                              void* d_out, int out_size, void* d_ws, size_t ws_size,
                              hipStream_t stream) {
    const float* x      = (const float*)d_in[0];
    const int*   first  = (const int*)d_in[1];
    const int*   second = (const int*)d_in[2];
    const float* dist   = (const float*)d_in[3];
    const float* mu     = (const float*)d_in[4];
    const float* sigma  = (const float*)d_in[5];
    const float* iw     = (const float*)d_in[6];
    const float* wself  = (const float*)d_in[7];
    const float* bself  = (const float*)d_in[8];
    float* out = (float*)d_out;

    char* ws = (char*)d_ws;
    unsigned short* WtB  = (unsigned short*)(ws);          // 172032 B
    int*            cnts = (int*)(ws + 172032);            // 120000 B
    float2*         msr  = (float2*)(ws + 292032);         // 160 B
    unsigned*       pk   = (unsigned*)(ws + 292192);       // 5760000 B -> ~6.05 MB

    k_prep<<<dim3(161), dim3(256), 0, stream>>>(iw, wself, mu, sigma, WtB, cnts, msr);
    k_scatter<<<dim3((N_PAIRS / 2 + 255) / 256), dim3(256), 0, stream>>>(
        first, second, dist, cnts, pk);
    k_main<<<dim3(N_ATOMS / BA), dim3(512), 0, stream>>>(
        x, cnts, pk, msr, WtB, bself, out);
}

// Round 13
// 125.017 us; speedup vs baseline: 1.3665x; 1.3665x over previous
//
#include <hip/hip_runtime.h>
#include <math.h>

#define N_ATOMS    30000
#define N_PAIRS    300000
#define CAP        48              // bucket capacity per atom; multiple of 16
#define NF         64
#define ND         20
#define K_ENV      1280            // 20nu * 64f (packed, no padding)
#define K_TOT      1344            // K_ENV + 64 self features
#define NKSTEP     42              // K_TOT / 32
#define HARD_CUT   6.5f
#define BA         16              // atoms per block in main kernel
#define ESTRIDE    1352            // env row stride in u16 (1344+8 pad -> bank spread)
#define D_LO       0.85f
#define D_SCALE    (5.65f / 65535.0f)
#define D_SCALE_I  (65535.0f / 5.65f)
#define NM1        ((unsigned)(N_ATOMS - 1))

typedef short    s16x8  __attribute__((ext_vector_type(8)));
typedef __bf16   bf16x8 __attribute__((ext_vector_type(8)));
typedef unsigned u32x4  __attribute__((ext_vector_type(4)));
typedef float    f32x4  __attribute__((ext_vector_type(4)));
typedef float    f32x16 __attribute__((ext_vector_type(16)));

__device__ __forceinline__ unsigned short f2bf(float x) {
    union { float f; unsigned u; } v; v.f = x;
    unsigned r = v.u + 0x7fffu + ((v.u >> 16) & 1u);   // RNE
    return (unsigned short)(r >> 16);
}
// pack two floats -> packed bf16 pair (a in low 16), RNE
__device__ __forceinline__ unsigned pkbf(float a, float b) {
    return (unsigned)f2bf(a) | ((unsigned)f2bf(b) << 16);
}
// sensitivity for one packed pair-slot, lane's nu
__device__ __forceinline__ float senseval(unsigned pu, int kidx, int cnt,
                                          float isig, float musig, bool nuok) {
    float d  = D_LO + (float)(pu & 0xffffu) * D_SCALE;
    float z  = __builtin_amdgcn_rcpf(d) * isig - musig;
    float co = __cosf(0.2416609733530613f * d);        // 0.5*pi/6.5
    float e  = __expf(-0.5f * z * z) * (co * co);
    return (nuok && kidx < cnt) ? e : 0.0f;
}

// ---------------------------------------------------------------------------
// K0: prep = pack weights into bf16 B-frag layout with phase-1 k'-permutation
// (blocks 0..41), zero cnts (42..159), msr (160), x -> packed-bf16 table
// (161..1098): xb16[a*32+c] = bf16(x[a,2c+1])<<16 | bf16(x[a,2c]).
// Weight perm (verified R9): k'<1280: t=k'/640, g=(k'%640)>>7, c=(k'&127)>>2,
// r=k'&3 -> nu=4g+r, f=2c+t ; k'>=1280: self row, f=k'-1280.
__global__ void k_prep(const float* __restrict__ iw, const float* __restrict__ wself,
                       const float* __restrict__ mu, const float* __restrict__ sigma,
                       const float* __restrict__ x,
                       unsigned short* __restrict__ WtB, int* __restrict__ cnts,
                       float2* __restrict__ msr, unsigned* __restrict__ xb16) {
    if (blockIdx.x < 42) {
        int idx = blockIdx.x * 256 + threadIdx.x;       // (ks*4+q)*64 + lane
        if (idx >= NKSTEP * 4 * 64) return;
        int l  = idx & 63;
        int q  = (idx >> 6) & 3;
        int ks = idx >> 8;
        int n  = q * 16 + (l & 15);
        int kb = ks * 32 + (l >> 4) * 8;
        u32x4 u;
        #pragma unroll
        for (int jj = 0; jj < 4; jj++) {
            unsigned short lo, hi;
            #pragma unroll
            for (int e = 0; e < 2; e++) {
                int k = kb + 2 * jj + e;
                float val;
                if (k < K_ENV) {
                    int t  = k / 640;
                    int rm = k - t * 640;
                    int g  = rm >> 7;
                    int c  = (rm & 127) >> 2;
                    int r  = k & 3;
                    int nu = 4 * g + r;
                    int f  = 2 * c + t;                  // even/odd tile split
                    val = iw[(nu * NF + n) * NF + f];
                } else {
                    val = wself[n * NF + (k - K_ENV)];
                }
                if (e == 0) lo = f2bf(val); else hi = f2bf(val);
            }
            u[jj] = (unsigned)lo | ((unsigned)hi << 16);
        }
        *(u32x4*)&WtB[idx * 8] = u;
    } else if (blockIdx.x < 160) {
        int i = (blockIdx.x - 42) * 256 + threadIdx.x;
        if (i < N_ATOMS) cnts[i] = 0;
    } else if (blockIdx.x == 160) {
        int i = threadIdx.x;
        if (i < ND) { float2 m; m.x = mu[i]; m.y = 1.0f / sigma[i]; msr[i] = m; }
    } else {
        int o = (blockIdx.x - 161) * 256 + threadIdx.x;  // uint4 of xb16
        if (o < N_ATOMS * 32 / 4) {
            int wbase = o * 4;                           // word wi covers floats 2wi,2wi+1
            const float* src = &x[(size_t)wbase * 2];
            float2 f0 = *(const float2*)(src);
            float2 f1 = *(const float2*)(src + 2);
            float2 f2 = *(const float2*)(src + 4);
            float2 f3 = *(const float2*)(src + 6);
            u32x4 u;
            u[0] = pkbf(f0.x, f0.y);
            u[1] = pkbf(f1.x, f1.y);
            u[2] = pkbf(f2.x, f2.y);
            u[3] = pkbf(f3.x, f3.y);
            *(u32x4*)&xb16[wbase] = u;
        }
    }
}

// ---------------------------------------------------------------------------
// K1: scatter pairs into per-atom buckets; pack (second<<16 | dist_u16).
// 2 pairs/thread, vectorized input loads.
__global__ void k_scatter(const int* __restrict__ first, const int* __restrict__ second,
                          const float* __restrict__ dist, int* __restrict__ cnts,
                          unsigned* __restrict__ pk) {
    int p = (blockIdx.x * 256 + threadIdx.x) * 2;
    if (p >= N_PAIRS) return;
    int2   f2 = *(const int2*)&first[p];
    int2   s2 = *(const int2*)&second[p];
    float2 d2 = *(const float2*)&dist[p];
    {
        int pos = atomicAdd(&cnts[f2.x], 1);
        if (pos < CAP) {
            unsigned du = min((unsigned)((d2.x - D_LO) * D_SCALE_I + 0.5f), 65535u);
            pk[(size_t)f2.x * CAP + pos] = ((unsigned)s2.x << 16) | du;
        }
    }
    {
        int pos = atomicAdd(&cnts[f2.y], 1);
        if (pos < CAP) {
            unsigned du = min((unsigned)((d2.y - D_LO) * D_SCALE_I + 0.5f), 65535u);
            pk[(size_t)f2.y * CAP + pos] = ((unsigned)s2.y << 16) | du;
        }
    }
}

// ---------------------------------------------------------------------------
// K2: fused sense + MFMA envsum + MFMA interaction matmul. 512 thr = 8 waves.
// R11 loop structure EXACTLY (R9/R12 lesson: cross-atom-loop live values get
// demoted to scratch). All staging in ext-vectors / named scalars.
// Phase 1: wave w handles atoms {2w,2w+1}. Per 16-pair K-step:
//   A = sense^T (8 exps inline, RNE pack), B = PRE-CONVERTED bf16 x rows via
//   4 B dword gathers (feats {2cl,2cl+1}), combined by single v_perm_b32 ops
//   -> even/odd tiles; 2x mfma_f32_32x32x16_bf16; C -> LDS in C-layout.
// Phase 2: waves 0..3: out[16 atoms][64] = env[16][1344] x WtB (16x16x32).
__global__ void __launch_bounds__(512, 6)
k_main(const unsigned* __restrict__ xb16, const int* __restrict__ cnts,
       const unsigned* __restrict__ pk, const float2* __restrict__ msr,
       const unsigned short* __restrict__ WtB, const float* __restrict__ bself,
       float* __restrict__ out) {
    __shared__ unsigned short env[BA * ESTRIDE];          // 43264 B -> 3 blocks/CU
    const int t  = threadIdx.x;
    const int w  = t >> 6;       // wave 0..7
    const int l  = t & 63;       // lane
    const int h  = l >> 5;       // half-wave (k-group)
    const int cl = l & 31;       // A: nu row   |  B/C: column
    const int a0 = blockIdx.x * BA;

    // lane-resident sense constants (nu = cl)
    float2 ms   = msr[min(cl, ND - 1)];
    const float isig  = ms.y;
    const float musig = ms.x * ms.y;
    const bool  nuok  = (cl < ND);
    const unsigned* xw = xb16 + cl;                       // lane's word column

    // ---- Phase 1: MFMA envsum (2 atoms per wave, sequential) ----
    #pragma unroll 1
    for (int ci = 0; ci < 2; ci++) {
        const int i = 2 * w + ci;
        const int a = a0 + i;
        const int cnt = min(cnts[a], CAP);
        const int nst = max((cnt + 15) >> 4, 1);
        const unsigned* gb = &pk[(size_t)a * CAP];
        f32x16 acc0 = {0.f}, acc1 = {0.f};
        #pragma unroll 1
        for (int ks = 0; ks < nst; ks++) {
            const int k0 = ks * 16 + h * 8;
            uint4 p0 = *(const uint4*)(gb + k0);          // 16B-aligned, h-uniform
            uint4 p1 = *(const uint4*)(gb + k0 + 4);
            // 8 dword gathers of pre-packed bf16 pairs (feats {2cl,2cl+1})
            unsigned g0 = xw[min(p0.x >> 16, NM1) * 32];
            unsigned g1 = xw[min(p0.y >> 16, NM1) * 32];
            unsigned g2 = xw[min(p0.z >> 16, NM1) * 32];
            unsigned g3 = xw[min(p0.w >> 16, NM1) * 32];
            unsigned g4 = xw[min(p1.x >> 16, NM1) * 32];
            unsigned g5 = xw[min(p1.y >> 16, NM1) * 32];
            unsigned g6 = xw[min(p1.z >> 16, NM1) * 32];
            unsigned g7 = xw[min(p1.w >> 16, NM1) * 32];
            u32x4 A, B0, B1;
            A[0] = pkbf(senseval(p0.x, k0 + 0, cnt, isig, musig, nuok),
                        senseval(p0.y, k0 + 1, cnt, isig, musig, nuok));
            A[1] = pkbf(senseval(p0.z, k0 + 2, cnt, isig, musig, nuok),
                        senseval(p0.w, k0 + 3, cnt, isig, musig, nuok));
            A[2] = pkbf(senseval(p1.x, k0 + 4, cnt, isig, musig, nuok),
                        senseval(p1.y, k0 + 5, cnt, isig, musig, nuok));
            A[3] = pkbf(senseval(p1.z, k0 + 6, cnt, isig, musig, nuok),
                        senseval(p1.w, k0 + 7, cnt, isig, musig, nuok));
            // v_perm lane-combines: low halves = even feats, high = odd feats
            B0[0] = __builtin_amdgcn_perm(g1, g0, 0x05040100u);
            B0[1] = __builtin_amdgcn_perm(g3, g2, 0x05040100u);
            B0[2] = __builtin_amdgcn_perm(g5, g4, 0x05040100u);
            B0[3] = __builtin_amdgcn_perm(g7, g6, 0x05040100u);
            B1[0] = __builtin_amdgcn_perm(g1, g0, 0x07060302u);
            B1[1] = __builtin_amdgcn_perm(g3, g2, 0x07060302u);
            B1[2] = __builtin_amdgcn_perm(g5, g4, 0x07060302u);
            B1[3] = __builtin_amdgcn_perm(g7, g6, 0x07060302u);
            acc0 = __builtin_amdgcn_mfma_f32_32x32x16_bf16(
                       __builtin_bit_cast(bf16x8, A),
                       __builtin_bit_cast(bf16x8, B0), acc0, 0, 0, 0);
            acc1 = __builtin_amdgcn_mfma_f32_32x32x16_bf16(
                       __builtin_bit_cast(bf16x8, A),
                       __builtin_bit_cast(bf16x8, B1), acc1, 0, 0, 0);
        }
        // C -> env LDS. C row = (reg&3)+8*(reg>>2)+4*h; g=2q+h holds rows
        // 4g..4g+3 (g<5 <=> row<20). k' = t*640 + g*128 + cl*4 + r.
        unsigned short* er = &env[i * ESTRIDE];
        #pragma unroll
        for (int q = 0; q < 3; q++) {
            int g = 2 * q + h;
            if (g < 5) {
                uint2 v0, v1;
                v0.x = pkbf(acc0[4 * q + 0], acc0[4 * q + 1]);
                v0.y = pkbf(acc0[4 * q + 2], acc0[4 * q + 3]);
                v1.x = pkbf(acc1[4 * q + 0], acc1[4 * q + 1]);
                v1.y = pkbf(acc1[4 * q + 2], acc1[4 * q + 3]);
                *(uint2*)&er[g * 128 + cl * 4]       = v0;
                *(uint2*)&er[640 + g * 128 + cl * 4] = v1;
            }
        }
        // self features (k'=1280..1343), from the bf16 table
        unsigned sw = xb16[(size_t)a * 32 + (l >> 1)];
        er[K_ENV + l] = (unsigned short)(sw >> ((l & 1) * 16));
    }
    __syncthreads();

    // ---- Phase 2: MFMA GEMM (waves 0..3) ----
    if (w < 4) {
        const int m16  = l & 15;     // atom row / out col
        const int quad = l >> 4;
        f32x4 acc = {0.f, 0.f, 0.f, 0.f};
        for (int ks = 0; ks < NKSTEP; ks++) {
            s16x8 afrag = *(const s16x8*)&env[m16 * ESTRIDE + ks * 32 + quad * 8];
            s16x8 bfrag = *(const s16x8*)&WtB[((ks * 4 + w) * 64 + l) * 8];
            acc = __builtin_amdgcn_mfma_f32_16x16x32_bf16(
                      __builtin_bit_cast(bf16x8, afrag),
                      __builtin_bit_cast(bf16x8, bfrag), acc, 0, 0, 0);
        }
        const float bs = bself[w * 16 + m16];
        #pragma unroll
        for (int r = 0; r < 4; r++) {
            int row = quad * 4 + r;                       // atom within block
            out[(size_t)(a0 + row) * NF + w * 16 + m16] = acc[r] + bs;
        }
    }
}

// ---------------------------------------------------------------------------
extern "C" void kernel_launch(void* const* d_in, const int* in_sizes, int n_in,
                              void* d_out, int out_size, void* d_ws, size_t ws_size,
                              hipStream_t stream) {
    const float* x      = (const float*)d_in[0];
    const int*   first  = (const int*)d_in[1];
    const int*   second = (const int*)d_in[2];
    const float* dist   = (const float*)d_in[3];
    const float* mu     = (const float*)d_in[4];
    const float* sigma  = (const float*)d_in[5];
    const float* iw     = (const float*)d_in[6];
    const float* wself  = (const float*)d_in[7];
    const float* bself  = (const float*)d_in[8];
    float* out = (float*)d_out;

    char* ws = (char*)d_ws;
    unsigned short* WtB  = (unsigned short*)(ws);          // 172032 B
    int*            cnts = (int*)(ws + 172032);            // 120000 B
    float2*         msr  = (float2*)(ws + 292032);         // 160 B
    unsigned*       pk   = (unsigned*)(ws + 292192);       // 5760000 B
    unsigned*       xb16 = (unsigned*)(ws + 6052192);      // 3840000 B -> ~9.9 MB

    k_prep<<<dim3(161 + (N_ATOMS * 8 + 255) / 256), dim3(256), 0, stream>>>(
        iw, wself, mu, sigma, x, WtB, cnts, msr, xb16);
    k_scatter<<<dim3((N_PAIRS / 2 + 255) / 256), dim3(256), 0, stream>>>(
        first, second, dist, cnts, pk);
    k_main<<<dim3(N_ATOMS / BA), dim3(512), 0, stream>>>(
        xb16, cnts, pk, msr, WtB, bself, out);
}